// Round 1
// baseline (418.005 us; speedup 1.0000x reference)
//
#include <hip/hip_runtime.h>
#include <math.h>

#define EPS_GS 1e-8f
#define RAD2DEG 57.29577951308232f
#define PI_F 3.14159265358979f

__device__ __forceinline__ float clip10(float x) {
    // ternary form preserves NaN (matches jnp.clip NaN propagation)
    x = x < -10.f ? -10.f : x;
    x = x >  10.f ?  10.f : x;
    return x;
}

// v_sqrt_f32 / v_rcp_f32 — ~1 ulp, single-instruction
__device__ __forceinline__ float fsqrt(float x) { return __builtin_amdgcn_sqrtf(x); }
__device__ __forceinline__ float frcp(float x)  { return __builtin_amdgcn_rcpf(x); }

// Abramowitz-Stegun 4.4.45: max error 6.76e-5 rad on [-1,1]
__device__ __forceinline__ float fast_acos(float x) {
    float ax = fabsf(x);
    float p = fmaf(ax, -0.0187293f, 0.0742610f);
    p = fmaf(ax, p, -0.2121144f);
    p = fmaf(ax, p, 1.5707288f);
    float pos = fsqrt(1.f - ax) * p;
    return x >= 0.f ? pos : PI_F - pos;
}

// v: 3x3 row-major (clipped). Columns: c0=(v0,v3,v6), c1=(v1,v4,v7), c2=(v2,v5,v8).
// R: row-major rotation, columns e1,e2,e3 (e3 sign-fixed by det).
__device__ __forceinline__ void gs_rotmat(const float* v, float* R) {
    float c0x = v[0], c0y = v[3], c0z = v[6];
    float c1x = v[1], c1y = v[4], c1z = v[7];
    float c2x = v[2], c2y = v[5], c2z = v[8];

    float s1 = fmaf(c0x, c0x, fmaf(c0y, c0y, c0z*c0z));
    float inv1 = frcp(fsqrt(s1) + EPS_GS);
    float e1x = c0x*inv1, e1y = c0y*inv1, e1z = c0z*inv1;

    float d = fmaf(e1x, c1x, fmaf(e1y, c1y, e1z*c1z));
    float u2x = fmaf(-d, e1x, c1x), u2y = fmaf(-d, e1y, c1y), u2z = fmaf(-d, e1z, c1z);
    float s2 = fmaf(u2x, u2x, fmaf(u2y, u2y, u2z*u2z));
    float inv2 = frcp(fsqrt(s2) + EPS_GS);
    float e2x = u2x*inv2, e2y = u2y*inv2, e2z = u2z*inv2;

    float d1 = fmaf(e1x, c2x, fmaf(e1y, c2y, e1z*c2z));
    float d2 = fmaf(e2x, c2x, fmaf(e2y, c2y, e2z*c2z));
    float u3x = fmaf(-d1, e1x, fmaf(-d2, e2x, c2x));
    float u3y = fmaf(-d1, e1y, fmaf(-d2, e2y, c2y));
    float u3z = fmaf(-d1, e1z, fmaf(-d2, e2z, c2z));
    float s3 = fmaf(u3x, u3x, fmaf(u3y, u3y, u3z*u3z));
    float inv3 = frcp(fsqrt(s3) + EPS_GS);
    float e3x = u3x*inv3, e3y = u3y*inv3, e3z = u3z*inv3;

    // det(Q) = e1 . (e2 x e3)
    float cxx = e2y*e3z - e2z*e3y;
    float cxy = e2z*e3x - e2x*e3z;
    float cxz = e2x*e3y - e2y*e3x;
    float det = fmaf(e1x, cxx, fmaf(e1y, cxy, e1z*cxz));
    if (det < 0.f) { e3x = -e3x; e3y = -e3y; e3z = -e3z; } // NaN<0 false -> keep

    R[0] = e1x; R[1] = e2x; R[2] = e3x;
    R[3] = e1y; R[4] = e2y; R[5] = e3y;
    R[6] = e1z; R[7] = e2z; R[8] = e3z;
}

__device__ __forceinline__ void accum_rot(const float* pr, const float* tg,
                                          float& lt, float& lf) {
    float pc[9], tc[9];
    #pragma unroll
    for (int m = 0; m < 9; ++m) { pc[m] = clip10(pr[m]); tc[m] = clip10(tg[m]); }

    float Rp[9], Rt[9];
    gs_rotmat(pc, Rp);
    gs_rotmat(tc, Rt);

    float chord = 0.f, tr = 0.f;
    #pragma unroll
    for (int m = 0; m < 9; ++m) {
        float d = Rp[m] - Rt[m];
        chord = fmaf(d, d, chord);
        tr    = fmaf(Rp[m], Rt[m], tr);
    }

    const float trLo = -3.0f + 1e-6f, trHi = 3.0f - 1e-6f;
    tr = tr < trLo ? trLo : (tr > trHi ? trHi : tr);
    float ca = (tr - 1.f) * 0.5f;
    const float cLo = -1.0f + 1e-7f, cHi = 1.0f - 1e-7f;
    ca = ca < cLo ? cLo : (ca > cHi ? cHi : ca);
    float ang = fast_acos(ca) * RAD2DEG;
    if (ang != ang) ang = 180.f;

    // orthogonality: AtA[i][j] = col_i . col_j of clipped pred matrix.
    // AtA symmetric: diag once, off-diag counted twice.
    float o = 0.f;
    #pragma unroll
    for (int i = 0; i < 3; ++i) {
        float dii = fmaf(pc[i], pc[i], fmaf(pc[3+i], pc[3+i], pc[6+i]*pc[6+i])) - 1.f;
        o = fmaf(dii, dii, o);
    }
    #pragma unroll
    for (int i = 0; i < 3; ++i) {
        #pragma unroll
        for (int j = i + 1; j < 3; ++j) {
            float s = fmaf(pc[i], pc[j], fmaf(pc[3+i], pc[3+j], pc[6+i]*pc[6+j]));
            float s2 = s + s;
            o = fmaf(s2, s, o);
        }
    }

    float l2 = 0.f, fb = 0.f;
    #pragma unroll
    for (int m = 0; m < 9; ++m) {
        l2 = fmaf(pc[m], pc[m], l2);
        float d = pc[m] - tg[m];   // fallback uses UNclipped target
        fb = fmaf(d, d, fb);
    }

    lt += fmaf(0.1f, ang, chord) + fmaf(0.01f, o, (1e-4f/9.f)*l2);
    lf += fb;
}

// 2 rotations per thread via float2 loads (9+9 x 8B, batched for MLP).
// Live data = 36 floats (vs 144 in the 4-rot float4 version) -> fits 128 VGPRs
// -> 4 waves/SIMD so HBM latency is hidden. Lane stride 72B: every byte of each
// touched 64B line is consumed by the wave's 9 loads (MSHR-merged in flight).
__global__ __launch_bounds__(256, 4)
void rot_loss_kernel(const float* __restrict__ pred, const float* __restrict__ targ,
                     double* __restrict__ acc, int B) {
    const int g    = blockIdx.x * blockDim.x + threadIdx.x; // pair-of-2 index
    const int base = g * 2;

    float lt = 0.f, lf = 0.f;

    if (base + 1 < B) {
        const float2* p2 = reinterpret_cast<const float2*>(pred) + (size_t)g * 9;
        const float2* t2 = reinterpret_cast<const float2*>(targ) + (size_t)g * 9;
        float2 pv[9], tv[9];
        #pragma unroll
        for (int j = 0; j < 9; ++j) pv[j] = p2[j];
        #pragma unroll
        for (int j = 0; j < 9; ++j) tv[j] = t2[j];

        {
            float a0[9] = {pv[0].x, pv[0].y, pv[1].x, pv[1].y, pv[2].x,
                           pv[2].y, pv[3].x, pv[3].y, pv[4].x};
            float b0[9] = {tv[0].x, tv[0].y, tv[1].x, tv[1].y, tv[2].x,
                           tv[2].y, tv[3].x, tv[3].y, tv[4].x};
            accum_rot(a0, b0, lt, lf);
        }
        {
            float a1[9] = {pv[4].y, pv[5].x, pv[5].y, pv[6].x, pv[6].y,
                           pv[7].x, pv[7].y, pv[8].x, pv[8].y};
            float b1[9] = {tv[4].y, tv[5].x, tv[5].y, tv[6].x, tv[6].y,
                           tv[7].x, tv[7].y, tv[8].x, tv[8].y};
            accum_rot(a1, b1, lt, lf);
        }
    } else if (base < B) {
        for (int r = base; r < B; ++r) {
            float a1[9], b1[9];
            for (int m = 0; m < 9; ++m) { a1[m] = pred[(size_t)r*9 + m]; b1[m] = targ[(size_t)r*9 + m]; }
            accum_rot(a1, b1, lt, lf);
        }
    }

    // wave-64 reduce
    #pragma unroll
    for (int off = 32; off > 0; off >>= 1) {
        lt += __shfl_down(lt, off, 64);
        lf += __shfl_down(lf, off, 64);
    }
    __shared__ float st[4], sf[4];
    const int lane = threadIdx.x & 63;
    const int wid  = threadIdx.x >> 6;
    if (lane == 0) { st[wid] = lt; sf[wid] = lf; }
    __syncthreads();
    if (threadIdx.x == 0) {
        float bt = st[0] + st[1] + st[2] + st[3];
        float bf = sf[0] + sf[1] + sf[2] + sf[3];
        unsafeAtomicAdd(&acc[0], (double)bt);  // HW global_atomic_add_f64
        unsafeAtomicAdd(&acc[1], (double)bf);
    }
}

__global__ void finalize_kernel(const double* __restrict__ acc,
                                float* __restrict__ out, int B) {
    if (threadIdx.x == 0 && blockIdx.x == 0) {
        double total = acc[0] / (double)B;
        double fb    = acc[1] / (9.0 * (double)B);
        out[0] = isnan(total) ? (float)fb : (float)total;
    }
}

extern "C" void kernel_launch(void* const* d_in, const int* in_sizes, int n_in,
                              void* d_out, int out_size, void* d_ws, size_t ws_size,
                              hipStream_t stream) {
    const float* pred = (const float*)d_in[0];
    const float* targ = (const float*)d_in[1];
    const int n = in_sizes[0];
    const int B = n / 9;

    double* acc = (double*)d_ws;
    hipMemsetAsync(d_ws, 0, 2 * sizeof(double), stream);

    const int npairs  = (B + 1) / 2;
    const int threads = 256;
    const int blocks  = (npairs + threads - 1) / threads;
    rot_loss_kernel<<<blocks, threads, 0, stream>>>(pred, targ, acc, B);
    finalize_kernel<<<1, 64, 0, stream>>>(acc, (float*)d_out, B);
}

// Round 2
// 309.354 us; speedup vs baseline: 1.3512x; 1.3512x over previous
//
#include <hip/hip_runtime.h>
#include <math.h>

#define EPS_GS 1e-8f
#define RAD2DEG 57.29577951308232f
#define PI_F 3.14159265358979f

constexpr int THREADS   = 256;
constexpr int TILE_ROTS = 512;                    // rotations per block-tile
constexpr int TILE_F    = TILE_ROTS * 9;          // 4608 floats = 18432 B per array
constexpr int TILE_F2   = TILE_F / 2;             // 2304 float2
constexpr int F2_PER_TH = TILE_F2 / THREADS;      // 9
constexpr int NSLOTS    = 16;                     // atomic spread slots (64B stride)

__device__ __forceinline__ float clip10(float x) {
    // ternary form preserves NaN (matches jnp.clip NaN propagation)
    x = x < -10.f ? -10.f : x;
    x = x >  10.f ?  10.f : x;
    return x;
}

// v_sqrt_f32 / v_rcp_f32 — ~1 ulp, single-instruction
__device__ __forceinline__ float fsqrt(float x) { return __builtin_amdgcn_sqrtf(x); }
__device__ __forceinline__ float frcp(float x)  { return __builtin_amdgcn_rcpf(x); }

// Abramowitz-Stegun 4.4.45: max error 6.76e-5 rad on [-1,1]
__device__ __forceinline__ float fast_acos(float x) {
    float ax = fabsf(x);
    float p = fmaf(ax, -0.0187293f, 0.0742610f);
    p = fmaf(ax, p, -0.2121144f);
    p = fmaf(ax, p, 1.5707288f);
    float pos = fsqrt(1.f - ax) * p;
    return x >= 0.f ? pos : PI_F - pos;
}

// v: 3x3 row-major (clipped). Columns: c0=(v0,v3,v6), c1=(v1,v4,v7), c2=(v2,v5,v8).
// R: row-major rotation, columns e1,e2,e3 (e3 sign-fixed by det).
__device__ __forceinline__ void gs_rotmat(const float* v, float* R) {
    float c0x = v[0], c0y = v[3], c0z = v[6];
    float c1x = v[1], c1y = v[4], c1z = v[7];
    float c2x = v[2], c2y = v[5], c2z = v[8];

    float s1 = fmaf(c0x, c0x, fmaf(c0y, c0y, c0z*c0z));
    float inv1 = frcp(fsqrt(s1) + EPS_GS);
    float e1x = c0x*inv1, e1y = c0y*inv1, e1z = c0z*inv1;

    float d = fmaf(e1x, c1x, fmaf(e1y, c1y, e1z*c1z));
    float u2x = fmaf(-d, e1x, c1x), u2y = fmaf(-d, e1y, c1y), u2z = fmaf(-d, e1z, c1z);
    float s2 = fmaf(u2x, u2x, fmaf(u2y, u2y, u2z*u2z));
    float inv2 = frcp(fsqrt(s2) + EPS_GS);
    float e2x = u2x*inv2, e2y = u2y*inv2, e2z = u2z*inv2;

    float d1 = fmaf(e1x, c2x, fmaf(e1y, c2y, e1z*c2z));
    float d2 = fmaf(e2x, c2x, fmaf(e2y, c2y, e2z*c2z));
    float u3x = fmaf(-d1, e1x, fmaf(-d2, e2x, c2x));
    float u3y = fmaf(-d1, e1y, fmaf(-d2, e2y, c2y));
    float u3z = fmaf(-d1, e1z, fmaf(-d2, e2z, c2z));
    float s3 = fmaf(u3x, u3x, fmaf(u3y, u3y, u3z*u3z));
    float inv3 = frcp(fsqrt(s3) + EPS_GS);
    float e3x = u3x*inv3, e3y = u3y*inv3, e3z = u3z*inv3;

    // det(Q) = e1 . (e2 x e3)
    float cxx = e2y*e3z - e2z*e3y;
    float cxy = e2z*e3x - e2x*e3z;
    float cxz = e2x*e3y - e2y*e3x;
    float det = fmaf(e1x, cxx, fmaf(e1y, cxy, e1z*cxz));
    if (det < 0.f) { e3x = -e3x; e3y = -e3y; e3z = -e3z; } // NaN<0 false -> keep

    R[0] = e1x; R[1] = e2x; R[2] = e3x;
    R[3] = e1y; R[4] = e2y; R[5] = e3y;
    R[6] = e1z; R[7] = e2z; R[8] = e3z;
}

__device__ __forceinline__ void accum_rot(const float* pr, const float* tg,
                                          float& lt, float& lf) {
    float pc[9], tc[9];
    #pragma unroll
    for (int m = 0; m < 9; ++m) { pc[m] = clip10(pr[m]); tc[m] = clip10(tg[m]); }

    float Rp[9], Rt[9];
    gs_rotmat(pc, Rp);
    gs_rotmat(tc, Rt);

    float chord = 0.f, tr = 0.f;
    #pragma unroll
    for (int m = 0; m < 9; ++m) {
        float d = Rp[m] - Rt[m];
        chord = fmaf(d, d, chord);
        tr    = fmaf(Rp[m], Rt[m], tr);
    }

    const float trLo = -3.0f + 1e-6f, trHi = 3.0f - 1e-6f;
    tr = tr < trLo ? trLo : (tr > trHi ? trHi : tr);
    float ca = (tr - 1.f) * 0.5f;
    const float cLo = -1.0f + 1e-7f, cHi = 1.0f - 1e-7f;
    ca = ca < cLo ? cLo : (ca > cHi ? cHi : ca);
    float ang = fast_acos(ca) * RAD2DEG;
    if (ang != ang) ang = 180.f;

    // orthogonality: AtA[i][j] = col_i . col_j of clipped pred matrix.
    // AtA symmetric: diag once, off-diag counted twice.
    float o = 0.f;
    #pragma unroll
    for (int i = 0; i < 3; ++i) {
        float dii = fmaf(pc[i], pc[i], fmaf(pc[3+i], pc[3+i], pc[6+i]*pc[6+i])) - 1.f;
        o = fmaf(dii, dii, o);
    }
    #pragma unroll
    for (int i = 0; i < 3; ++i) {
        #pragma unroll
        for (int j = i + 1; j < 3; ++j) {
            float s = fmaf(pc[i], pc[j], fmaf(pc[3+i], pc[3+j], pc[6+i]*pc[6+j]));
            float s2 = s + s;
            o = fmaf(s2, s, o);
        }
    }

    float l2 = 0.f, fb = 0.f;
    #pragma unroll
    for (int m = 0; m < 9; ++m) {
        l2 = fmaf(pc[m], pc[m], l2);
        float d = pc[m] - tg[m];   // fallback uses UNclipped target
        fb = fmaf(d, d, fb);
    }

    lt += fmaf(0.1f, ang, chord) + fmaf(0.01f, o, (1e-4f/9.f)*l2);
    lf += fb;
}

// Coalesced-staged version: each block stages a 512-rotation tile into LDS with
// perfectly-coalesced float2 loads (lane stride 8B -> one 512B segment per wave
// instr), then gathers per-rotation 9-float rows from LDS. Row stride 9 dwords
// across 32 banks: gcd(9,32)=1 -> 2 lanes/bank (free on CDNA4).
__global__ __launch_bounds__(THREADS, 4)
void rot_loss_kernel(const float* __restrict__ pred, const float* __restrict__ targ,
                     double* __restrict__ acc, int B) {
    __shared__ float sp[TILE_F];
    __shared__ float sq[TILE_F];
    __shared__ float rsum_t[4], rsum_f[4];

    const int tid = threadIdx.x;
    const long long rot0 = (long long)blockIdx.x * TILE_ROTS;
    const long long rem64 = (long long)B - rot0;
    const int rem = rem64 > TILE_ROTS ? TILE_ROTS : (int)rem64;

    float lt = 0.f, lf = 0.f;

    if (rem == TILE_ROTS) {
        const float2* p2 = reinterpret_cast<const float2*>(pred + rot0 * 9);
        const float2* q2 = reinterpret_cast<const float2*>(targ + rot0 * 9);
        // batch all 18 coalesced loads first -> max memory-level parallelism
        float2 pv[F2_PER_TH], tv[F2_PER_TH];
        #pragma unroll
        for (int k = 0; k < F2_PER_TH; ++k) pv[k] = p2[tid + k*THREADS];
        #pragma unroll
        for (int k = 0; k < F2_PER_TH; ++k) tv[k] = q2[tid + k*THREADS];
        float2* sp2 = reinterpret_cast<float2*>(sp);
        float2* sq2 = reinterpret_cast<float2*>(sq);
        #pragma unroll
        for (int k = 0; k < F2_PER_TH; ++k) {
            sp2[tid + k*THREADS] = pv[k];
            sq2[tid + k*THREADS] = tv[k];
        }
        __syncthreads();
        #pragma unroll
        for (int rr = 0; rr < 2; ++rr) {
            const int r = tid + rr*THREADS;
            accum_rot(&sp[9*r], &sq[9*r], lt, lf);
        }
    } else if (rem > 0) {
        // tail tile: direct (uncoalesced) loads, correctness only
        for (int r = tid; r < rem; r += THREADS) {
            float a1[9], b1[9];
            const float* pp = pred + (rot0 + r) * 9;
            const float* qq = targ + (rot0 + r) * 9;
            for (int m = 0; m < 9; ++m) { a1[m] = pp[m]; b1[m] = qq[m]; }
            accum_rot(a1, b1, lt, lf);
        }
    }

    // wave-64 reduce
    #pragma unroll
    for (int off = 32; off > 0; off >>= 1) {
        lt += __shfl_down(lt, off, 64);
        lf += __shfl_down(lf, off, 64);
    }
    const int lane = tid & 63;
    const int wid  = tid >> 6;
    if (lane == 0) { rsum_t[wid] = lt; rsum_f[wid] = lf; }
    __syncthreads();
    if (tid == 0) {
        float bt = rsum_t[0] + rsum_t[1] + rsum_t[2] + rsum_t[3];
        float bf = rsum_f[0] + rsum_f[1] + rsum_f[2] + rsum_f[3];
        // spread atomics over 16 cache-line-strided slots to avoid
        // same-address f64 atomic serialization at the coherence point
        double* slot = acc + (size_t)(blockIdx.x & (NSLOTS - 1)) * 8;
        unsafeAtomicAdd(&slot[0], (double)bt);  // HW global_atomic_add_f64
        unsafeAtomicAdd(&slot[1], (double)bf);
    }
}

__global__ void finalize_kernel(const double* __restrict__ acc,
                                float* __restrict__ out, int B) {
    if (threadIdx.x == 0 && blockIdx.x == 0) {
        double t = 0.0, f = 0.0;
        for (int s = 0; s < NSLOTS; ++s) { t += acc[s*8]; f += acc[s*8 + 1]; }
        double total = t / (double)B;
        double fb    = f / (9.0 * (double)B);
        out[0] = isnan(total) ? (float)fb : (float)total;
    }
}

extern "C" void kernel_launch(void* const* d_in, const int* in_sizes, int n_in,
                              void* d_out, int out_size, void* d_ws, size_t ws_size,
                              hipStream_t stream) {
    const float* pred = (const float*)d_in[0];
    const float* targ = (const float*)d_in[1];
    const int n = in_sizes[0];
    const int B = n / 9;

    double* acc = (double*)d_ws;
    hipMemsetAsync(d_ws, 0, NSLOTS * 8 * sizeof(double), stream);

    const int blocks = (B + TILE_ROTS - 1) / TILE_ROTS;
    rot_loss_kernel<<<blocks, THREADS, 0, stream>>>(pred, targ, acc, B);
    finalize_kernel<<<1, 64, 0, stream>>>(acc, (float*)d_out, B);
}